// Round 8
// baseline (309.900 us; speedup 1.0000x reference)
//
#include <hip/hip_runtime.h>
#include <math.h>

#define NN 50000
#define NE 500000
#define NF 128
#define NO 16
#define SCAN_B 1024
#define NPART 16
#define EBL 1954     // (NE+255)/256

static_assert(NN < 65536, "src must fit u16");

typedef _Float16 f16x8 __attribute__((ext_vector_type(8)));
typedef _Float16 f16x4 __attribute__((ext_vector_type(4)));
typedef float f32x4 __attribute__((ext_vector_type(4)));

union HU { unsigned short u; _Float16 h; };

__device__ inline float rec_w(unsigned int rec) {
    HU cu; cu.u = (unsigned short)(rec >> 16);
    return (float)cu.h;
}

// ---------------- graph preprocessing (atomic-light CSR build) ----------------

// pass 1: per-edge rank within (partition, dst); spare blocks transpose W1/W2 to fp16
__global__ void k_count_rank(const int* __restrict__ dst, int* __restrict__ pcnt,
                             int* __restrict__ rank, int E,
                             const float* __restrict__ W1, const float* __restrict__ W2,
                             _Float16* __restrict__ W1T, _Float16* __restrict__ W2T) {
    int b = blockIdx.x;
    if (b < EBL) {
        int part = b & (NPART - 1);
        int e = b * 256 + threadIdx.x;
        if (e < E) {
            int d = dst[e];
            rank[e] = atomicAdd(&pcnt[part * NN + d], 1);
        }
    } else {
        int idx = (b - EBL) * 256 + threadIdx.x;   // [0,16384)
        int r = idx >> 7, c = idx & 127;
        W1T[(size_t)c * NF + r] = (_Float16)W1[idx];
        W2T[(size_t)c * NF + r] = (_Float16)W2[idx];
    }
}

// pass 2: per-node partition bases (in place) + block-level exclusive scan of totals
__global__ void k_scan1f(int* __restrict__ pcnt, int* __restrict__ offs_p,
                         int* __restrict__ bsums, int N) {
    __shared__ int sm[SCAN_B];
    int t = threadIdx.x;
    int i = blockIdx.x * SCAN_B + t;
    int c = 0;
    if (i < N) {
        int run = 0;
#pragma unroll
        for (int p = 0; p < NPART; ++p) {
            int v = pcnt[p * NN + i];
            pcnt[p * NN + i] = run;
            run += v;
        }
        c = run;
    }
    sm[t] = c;
    __syncthreads();
    for (int off = 1; off < SCAN_B; off <<= 1) {
        int x = (t >= off) ? sm[t - off] : 0;
        __syncthreads();
        sm[t] += x;
        __syncthreads();
    }
    if (i < N) offs_p[i] = sm[t] - c;
    if (t == SCAN_B - 1) bsums[blockIdx.x] = sm[t];
}

// 64-lane shuffle scan (NB=49 <= 64)
__global__ void k_scan2(int* __restrict__ bsums, int NB) {
    int t = threadIdx.x;
    int v = (t < NB) ? bsums[t] : 0;
    int orig = v;
#pragma unroll
    for (int off = 1; off < 64; off <<= 1) {
        int u = __shfl_up(v, off, 64);
        if (t >= off) v += u;
    }
    if (t < NB) bsums[t] = v - orig;
}

// pass 3: atomic-free scatter of packed 4B {src:u16, ew:fp16} records.
// Base merge (offs_p + bsums) folded in: both tables are small & L2-resident.
__global__ void k_scatter(const int* __restrict__ src, const int* __restrict__ dst,
                          const float* __restrict__ ew, const int* __restrict__ pcnt,
                          const int* __restrict__ rank,
                          const int* __restrict__ offs_p, const int* __restrict__ bsums,
                          unsigned int* __restrict__ erec, int E) {
    int part = blockIdx.x & (NPART - 1);
    int e = blockIdx.x * blockDim.x + threadIdx.x;
    if (e < E) {
        int d = dst[e];
        int pos = offs_p[d] + bsums[d >> 10] + pcnt[part * NN + d] + rank[e];
        HU cu; cu.h = (_Float16)ew[e];
        erec[pos] = (unsigned int)src[e] | ((unsigned int)cu.u << 16);
    }
}

// pass 4: deg from CSR -> dinv; also emits final offs
__global__ void k_dinv_csr(const unsigned int* __restrict__ erec,
                           const int* __restrict__ offs_p, const int* __restrict__ bsums,
                           int* __restrict__ offs_f, float* __restrict__ dinv, int N, int E) {
    int n = blockIdx.x * blockDim.x + threadIdx.x;
    if (n < N) {
        int s = offs_p[n] + bsums[n >> 10];
        int e = (n + 1 < N) ? offs_p[n + 1] + bsums[(n + 1) >> 10] : E;
        offs_f[n] = s;
        if (n == N - 1) offs_f[N] = E;
        float deg = 1.0f;
        for (int j = s; j < e; ++j) deg += rec_w(erec[j]);
        dinv[n] = rsqrtf(deg);
    }
}

// ---------------- MFMA GEMM: Z[M,128](fp16, row-major) = dinv ⊙ (X @ W) ----------------

__device__ inline f16x8 afrag_load(const float* X, int row, int k0) {
    const float4* p = (const float4*)(X + (size_t)row * NF + k0);
    float4 a = p[0], b = p[1];
    f16x8 r;
    r[0] = (_Float16)a.x; r[1] = (_Float16)a.y; r[2] = (_Float16)a.z; r[3] = (_Float16)a.w;
    r[4] = (_Float16)b.x; r[5] = (_Float16)b.y; r[6] = (_Float16)b.z; r[7] = (_Float16)b.w;
    return r;
}
__device__ inline f16x8 afrag_load(const _Float16* X, int row, int k0) {
    return *(const f16x8*)(X + (size_t)row * NF + k0);
}

template <typename TA>
__global__ __launch_bounds__(256) void k_gemm_mfma(const TA* __restrict__ X,
                                                   const _Float16* __restrict__ WT,
                                                   const float* __restrict__ dinv,
                                                   _Float16* __restrict__ Z, int M) {
    __shared__ _Float16 ls[4][16 * 136];      // padded stride 136 halves
    const int tid  = threadIdx.x;
    const int w    = tid >> 6;
    const int lane = tid & 63;
    const int n16  = lane & 15;
    const int quad = lane >> 4;
    const int r0   = blockIdx.x * 64 + w * 16;

    int arow = r0 + n16; if (arow > M - 1) arow = M - 1;

    f32x4 acc[8];
#pragma unroll
    for (int c = 0; c < 8; ++c) acc[c] = (f32x4){0.f, 0.f, 0.f, 0.f};

#pragma unroll
    for (int kk = 0; kk < 4; ++kk) {
        int k0 = kk * 32 + quad * 8;
        f16x8 a = afrag_load(X, arow, k0);
#pragma unroll
        for (int c = 0; c < 8; ++c) {
            f16x8 b = *(const f16x8*)(WT + (size_t)(c * 16 + n16) * NF + k0);
            acc[c] = __builtin_amdgcn_mfma_f32_16x16x32_f16(a, b, acc[c], 0, 0, 0);
        }
    }

    // epilogue: scale by dinv[row], fp16, repack via LDS for coalesced stores
#pragma unroll
    for (int reg = 0; reg < 4; ++reg) {
        int lrow = quad * 4 + reg;
        int grow = r0 + lrow; if (grow > M - 1) grow = M - 1;
        float di = dinv[grow];
#pragma unroll
        for (int c = 0; c < 8; ++c)
            ls[w][lrow * 136 + c * 16 + n16] = (_Float16)(acc[c][reg] * di);
    }
    __syncthreads();
#pragma unroll
    for (int i = 0; i < 4; ++i) {
        int off16 = i * 64 + lane;            // 16B chunk index in this wave's tile
        int row = off16 >> 4;
        int col = off16 & 15;
        int grow = r0 + row;
        if (grow < M) {
            f16x8 v = *(const f16x8*)(&ls[w][row * 136 + col * 8]);
            *(f16x8*)(Z + (size_t)grow * NF + col * 8) = v;
        }
    }
}

// ---------------- aggregation: line-granular slice + 8-edge 8B gathers ----------------
// slice = blockIdx & 3 -> features [slice*32, slice*32+32) = one 64B line per row.
// Wave lane = (eslot[0..8), li[0..8)): gather instr covers 8 edges x 64B.
// Round-robin block->XCD dispatch pins each slice's 3.2MB line set to 2 XCD L2s.
__global__ __launch_bounds__(256) void k_agg_s32(const _Float16* __restrict__ z,
                                                 const float* __restrict__ dinv,
                                                 const int* __restrict__ offs,
                                                 const unsigned int* __restrict__ erec,
                                                 const float* __restrict__ bias,
                                                 _Float16* __restrict__ hout, int relu) {
    const int tid   = threadIdx.x;
    const int lane  = tid & 63;
    const int eslot = lane >> 3;     // 0..7 edge slot
    const int li    = lane & 7;      // 4-feature chunk within slice
    const int slice = blockIdx.x & 3;
    int n = __builtin_amdgcn_readfirstlane((blockIdx.x >> 2) * 4 + (tid >> 6));

    const int fbase = slice * 32 + li * 4;

    float a0 = 0.f, a1 = 0.f, a2 = 0.f, a3 = 0.f;

    int s = offs[n], e = offs[n + 1];
    for (int base = s; base < e; base += 64) {
        int cnt = e - base; if (cnt > 64) cnt = 64;
        unsigned int rec = 0u;
        if (lane < cnt) rec = erec[base + lane];
        int   my_s = rec & 0xFFFF;
        float my_w = rec_w(rec);
        int k = 0;
        for (; k + 7 < cnt; k += 8) {
            int el = k + eslot;
            int   s0 = __shfl(my_s, el, 64);
            float w0 = __shfl(my_w, el, 64);
            f16x4 v = *(const f16x4*)(z + ((size_t)s0 << 7) + fbase);
            a0 = fmaf((float)v[0], w0, a0); a1 = fmaf((float)v[1], w0, a1);
            a2 = fmaf((float)v[2], w0, a2); a3 = fmaf((float)v[3], w0, a3);
        }
        if (k < cnt) {
            int el = k + eslot;
            int ec = el < cnt ? el : cnt - 1;
            int   s0 = __shfl(my_s, ec, 64);
            float wt = __shfl(my_w, ec, 64);
            float w0 = (el < cnt) ? wt : 0.0f;
            f16x4 v = *(const f16x4*)(z + ((size_t)s0 << 7) + fbase);
            a0 = fmaf((float)v[0], w0, a0); a1 = fmaf((float)v[1], w0, a1);
            a2 = fmaf((float)v[2], w0, a2); a3 = fmaf((float)v[3], w0, a3);
        }
    }
    // reduce across the 8 edge slots (lane bits 3,4,5)
    a0 += __shfl_xor(a0, 8, 64); a0 += __shfl_xor(a0, 16, 64); a0 += __shfl_xor(a0, 32, 64);
    a1 += __shfl_xor(a1, 8, 64); a1 += __shfl_xor(a1, 16, 64); a1 += __shfl_xor(a1, 32, 64);
    a2 += __shfl_xor(a2, 8, 64); a2 += __shfl_xor(a2, 16, 64); a2 += __shfl_xor(a2, 32, 64);
    a3 += __shfl_xor(a3, 8, 64); a3 += __shfl_xor(a3, 16, 64); a3 += __shfl_xor(a3, 32, 64);

    // self + bias + relu; lanes with eslot==0 store
    f16x4 sv = *(const f16x4*)(z + ((size_t)n << 7) + fbase);
    float di = dinv[n];
    float4 bb = *(const float4*)(bias + fbase);
    float r0 = fmaf(di, (float)sv[0] + a0, bb.x);
    float r1 = fmaf(di, (float)sv[1] + a1, bb.y);
    float r2 = fmaf(di, (float)sv[2] + a2, bb.z);
    float r3 = fmaf(di, (float)sv[3] + a3, bb.w);
    if (relu) {
        r0 = fmaxf(r0, 0.0f); r1 = fmaxf(r1, 0.0f);
        r2 = fmaxf(r2, 0.0f); r3 = fmaxf(r3, 0.0f);
    }
    if (eslot == 0) {
        f16x4 o;
        o[0] = (_Float16)r0; o[1] = (_Float16)r1;
        o[2] = (_Float16)r2; o[3] = (_Float16)r3;
        *(f16x4*)(hout + ((size_t)n << 7) + fbase) = o;
    }
}

// ---------------- GEMM: Z3[M,16](fp16) = dinv ⊙ (H[M,128](fp16) @ W3[128,16]) ----------------
__global__ __launch_bounds__(256) void k_gemm16(const _Float16* __restrict__ H,
                                                const float* __restrict__ W3,
                                                const float* __restrict__ dinv,
                                                _Float16* __restrict__ Z3, int M) {
    __shared__ float Wl[NF * NO];
    __shared__ float Hs[16 * 132];
    int tid = threadIdx.x;
    for (int i = tid; i < NF * NO; i += 256) Wl[i] = W3[i];
    int n0 = blockIdx.x * 16;
    {
        int row = tid >> 4, h8 = tid & 15;
        int gr = n0 + row; if (gr > M - 1) gr = M - 1;
        f16x8 v = *(const f16x8*)(H + (size_t)gr * NF + h8 * 8);
        float4 f0 = {(float)v[0], (float)v[1], (float)v[2], (float)v[3]};
        float4 f1 = {(float)v[4], (float)v[5], (float)v[6], (float)v[7]};
        *(float4*)(&Hs[row * 132 + h8 * 8])     = f0;
        *(float4*)(&Hs[row * 132 + h8 * 8 + 4]) = f1;
    }
    __syncthreads();
    int ln = tid >> 4, c = tid & 15;
    float acc = 0.0f;
#pragma unroll 8
    for (int k = 0; k < NF; ++k) acc = fmaf(Hs[ln * 132 + k], Wl[k * NO + c], acc);
    int n = n0 + ln;
    if (n < M) Z3[(size_t)n * NO + c] = (_Float16)(acc * dinv[n]);
}

// ---------------- final aggregation (16-wide, fp16 table) + bias + log_softmax ----------------
__global__ __launch_bounds__(256) void k_agg16_ls(const _Float16* __restrict__ z3,
                                                  const float* __restrict__ dinv,
                                                  const int* __restrict__ offs,
                                                  const unsigned int* __restrict__ erec,
                                                  const float* __restrict__ bias,
                                                  float* __restrict__ out) {
    int tid = threadIdx.x;
    int ln = tid >> 4, c = tid & 15;
    int n = blockIdx.x * 16 + ln;
    float acc = (float)z3[((size_t)n << 4) + c];
    int s = offs[n], e = offs[n + 1];
    int j = s;
    for (; j + 1 < e; j += 2) {
        unsigned int r0 = erec[j], r1 = erec[j + 1];
        acc = fmaf((float)z3[((size_t)(r0 & 0xFFFF) << 4) + c], rec_w(r0), acc);
        acc = fmaf((float)z3[((size_t)(r1 & 0xFFFF) << 4) + c], rec_w(r1), acc);
    }
    if (j < e) {
        unsigned int r0 = erec[j];
        acc = fmaf((float)z3[((size_t)(r0 & 0xFFFF) << 4) + c], rec_w(r0), acc);
    }
    acc = fmaf(dinv[n], acc, bias[c]);
    float m = acc;
#pragma unroll
    for (int off = 8; off > 0; off >>= 1) m = fmaxf(m, __shfl_xor(m, off, 16));
    float ex = expf(acc - m);
    float ss = ex;
#pragma unroll
    for (int off = 8; off > 0; off >>= 1) ss += __shfl_xor(ss, off, 16);
    out[(size_t)n * NO + c] = acc - m - logf(ss);
}

// ---------------- launch ----------------

extern "C" void kernel_launch(void* const* d_in, const int* in_sizes, int n_in,
                              void* d_out, int out_size, void* d_ws, size_t ws_size,
                              hipStream_t stream) {
    const float* x   = (const float*)d_in[0];
    const int*   esrc= (const int*)  d_in[1];
    const int*   edst= (const int*)  d_in[2];
    const float* ew  = (const float*)d_in[3];
    const float* W1  = (const float*)d_in[4];
    const float* b1  = (const float*)d_in[5];
    const float* W2  = (const float*)d_in[6];
    const float* b2  = (const float*)d_in[7];
    const float* W3  = (const float*)d_in[8];
    const float* b3  = (const float*)d_in[9];
    float* out = (float*)d_out;

    // workspace carve (z 256B-row aligned: ws base is page-aligned)
    char* p = (char*)d_ws;
    _Float16* z   = (_Float16*)p; p += (size_t)NN * NF * 2;   // row-major, 12.8 MB
    _Float16* h   = (_Float16*)p; p += (size_t)NN * NF * 2;   // row-major, 12.8 MB
    _Float16* z3  = (_Float16*)p; p += (size_t)NN * NO * 2;   // 1.6 MB
    float* dinv   = (float*)p; p += (size_t)NN * 4;
    unsigned int* erec = (unsigned int*)p; p += (size_t)NE * 4;  // packed 4B records
    int*   rank   = (int*)p;   p += (size_t)NE * 4;
    int*   pcnt   = (int*)p;   p += (size_t)NPART * NN * 4;   // 3.2 MB
    int*   offs_p = (int*)p;   p += (size_t)(NN + 1) * 4;
    int*   offs_f = (int*)p;   p += (size_t)(NN + 1) * 4;
    int*   bsums  = (int*)p;   p += 256;
    _Float16* W1T = (_Float16*)p; p += (size_t)NF * NF * 2;
    _Float16* W2T = (_Float16*)p; p += (size_t)NF * NF * 2;

    const int NB  = (NN + SCAN_B - 1) / SCAN_B;   // 49
    const int NBL = (NN + 255) / 256;

    hipMemsetAsync(pcnt, 0, (size_t)NPART * NN * 4, stream);

    k_count_rank<<<EBL + 64, 256, 0, stream>>>(edst, pcnt, rank, NE, W1, W2, W1T, W2T);
    k_scan1f<<<NB, SCAN_B, 0, stream>>>(pcnt, offs_p, bsums, NN);
    k_scan2<<<1, 64, 0, stream>>>(bsums, NB);
    k_scatter<<<EBL, 256, 0, stream>>>(esrc, edst, ew, pcnt, rank, offs_p, bsums, erec, NE);
    k_dinv_csr<<<NBL, 256, 0, stream>>>(erec, offs_p, bsums, offs_f, dinv, NN, NE);

    const int AGG_GRID = (NN / 4) * 4;   // 50000 blocks: (node_group)*4 + slice
    // layer 1
    k_gemm_mfma<float><<<(NN + 63) / 64, 256, 0, stream>>>(x, W1T, dinv, z, NN);
    k_agg_s32<<<AGG_GRID, 256, 0, stream>>>(z, dinv, offs_f, erec, b1, h, 1);
    // layer 2
    k_gemm_mfma<_Float16><<<(NN + 63) / 64, 256, 0, stream>>>(h, W2T, dinv, z, NN);
    k_agg_s32<<<AGG_GRID, 256, 0, stream>>>(z, dinv, offs_f, erec, b2, h, 1);
    // layer 3
    k_gemm16<<<(NN + 15) / 16, 256, 0, stream>>>(h, W3, dinv, z3, NN);
    k_agg16_ls<<<NN / 16, 256, 0, stream>>>(z3, dinv, offs_f, erec, b3, out);
}

// Round 9
// 273.274 us; speedup vs baseline: 1.1340x; 1.1340x over previous
//
#include <hip/hip_runtime.h>
#include <math.h>

#define NN 50000
#define NE 500000
#define NF 128
#define NO 16
#define SCAN_B 1024
#define NB_SCAN 49   // (NN+SCAN_B-1)/SCAN_B
#define NPART 16
#define EBL 1954     // (NE+255)/256

static_assert(NN < 65536, "src must fit u16");

typedef _Float16 f16x8 __attribute__((ext_vector_type(8)));
typedef _Float16 f16x4 __attribute__((ext_vector_type(4)));
typedef float f32x4 __attribute__((ext_vector_type(4)));

union HU { unsigned short u; _Float16 h; };

__device__ inline float rec_w(unsigned int rec) {
    HU cu; cu.u = (unsigned short)(rec >> 16);
    return (float)cu.h;
}

// ---------------- graph preprocessing (atomic-light CSR build) ----------------

// pass 1: per-edge rank within (partition, dst) + partitioned weighted-degree
// accumulation; spare blocks transpose W1/W2 to fp16.
__global__ void k_count_rank(const int* __restrict__ dst, const float* __restrict__ ew,
                             int* __restrict__ pcnt, float* __restrict__ pdeg,
                             int* __restrict__ rank, int E,
                             const float* __restrict__ W1, const float* __restrict__ W2,
                             _Float16* __restrict__ W1T, _Float16* __restrict__ W2T) {
    int b = blockIdx.x;
    if (b < EBL) {
        int part = b & (NPART - 1);
        int e = b * 256 + threadIdx.x;
        if (e < E) {
            int d = dst[e];
            rank[e] = atomicAdd(&pcnt[part * NN + d], 1);
            atomicAdd(&pdeg[part * NN + d], ew[e]);
        }
    } else {
        int idx = (b - EBL) * 256 + threadIdx.x;   // [0,16384)
        int r = idx >> 7, c = idx & 127;
        W1T[(size_t)c * NF + r] = (_Float16)W1[idx];
        W2T[(size_t)c * NF + r] = (_Float16)W2[idx];
    }
}

// pass 2: per-node partition bases (in place), dinv from pdeg, block scan of
// totals, and the 49-block top-level scan folded in via last-block pattern
// (agent-scope atomics for cross-XCD visibility).
__global__ void k_scan1f(int* __restrict__ pcnt, const float* __restrict__ pdeg,
                         int* __restrict__ offs_p, int* __restrict__ bsums,
                         float* __restrict__ dinv, int* __restrict__ done) {
    __shared__ int sm[SCAN_B];
    __shared__ int isLast;
    int t = threadIdx.x;
    int i = blockIdx.x * SCAN_B + t;
    int c = 0;
    if (i < NN) {
        int run = 0;
#pragma unroll
        for (int p = 0; p < NPART; ++p) {
            int v = pcnt[p * NN + i];
            pcnt[p * NN + i] = run;
            run += v;
        }
        c = run;
        float deg = 1.0f;   // self-loop weight
#pragma unroll
        for (int p = 0; p < NPART; ++p) deg += pdeg[p * NN + i];
        dinv[i] = rsqrtf(deg);
    }
    sm[t] = c;
    __syncthreads();
    for (int off = 1; off < SCAN_B; off <<= 1) {
        int x = (t >= off) ? sm[t - off] : 0;
        __syncthreads();
        sm[t] += x;
        __syncthreads();
    }
    if (i < NN) offs_p[i] = sm[t] - c;
    if (t == SCAN_B - 1) {
        __hip_atomic_store(&bsums[blockIdx.x], sm[t], __ATOMIC_RELEASE,
                           __HIP_MEMORY_SCOPE_AGENT);
        int old = __hip_atomic_fetch_add(done, 1, __ATOMIC_ACQ_REL,
                                         __HIP_MEMORY_SCOPE_AGENT);
        isLast = (old == (int)gridDim.x - 1) ? 1 : 0;
    }
    __syncthreads();
    if (isLast && t < 64) {
        int v = (t < NB_SCAN) ? __hip_atomic_load(&bsums[t], __ATOMIC_ACQUIRE,
                                                  __HIP_MEMORY_SCOPE_AGENT) : 0;
        int orig = v;
#pragma unroll
        for (int off = 1; off < 64; off <<= 1) {
            int u = __shfl_up(v, off, 64);
            if (t >= off) v += u;
        }
        if (t < NB_SCAN)
            __hip_atomic_store(&bsums[t], v - orig, __ATOMIC_RELEASE,
                               __HIP_MEMORY_SCOPE_AGENT);
    }
}

// pass 3: atomic-free scatter of packed 4B {src:u16, ew:fp16} records
__global__ void k_scatter(const int* __restrict__ src, const int* __restrict__ dst,
                          const float* __restrict__ ew, const int* __restrict__ pcnt,
                          const int* __restrict__ rank,
                          const int* __restrict__ offs_p, const int* __restrict__ bsums,
                          unsigned int* __restrict__ erec, int E) {
    int part = blockIdx.x & (NPART - 1);
    int e = blockIdx.x * blockDim.x + threadIdx.x;
    if (e < E) {
        int d = dst[e];
        int pos = offs_p[d] + bsums[d >> 10] + pcnt[part * NN + d] + rank[e];
        HU cu; cu.h = (_Float16)ew[e];
        erec[pos] = (unsigned int)src[e] | ((unsigned int)cu.u << 16);
    }
}

// ---------------- MFMA GEMM: Z[M,128](fp16, row-major) = dinv ⊙ (X @ W) ----------------

__device__ inline f16x8 afrag_load(const float* X, int row, int k0) {
    const float4* p = (const float4*)(X + (size_t)row * NF + k0);
    float4 a = p[0], b = p[1];
    f16x8 r;
    r[0] = (_Float16)a.x; r[1] = (_Float16)a.y; r[2] = (_Float16)a.z; r[3] = (_Float16)a.w;
    r[4] = (_Float16)b.x; r[5] = (_Float16)b.y; r[6] = (_Float16)b.z; r[7] = (_Float16)b.w;
    return r;
}
__device__ inline f16x8 afrag_load(const _Float16* X, int row, int k0) {
    return *(const f16x8*)(X + (size_t)row * NF + k0);
}

template <typename TA>
__global__ __launch_bounds__(256) void k_gemm_mfma(const TA* __restrict__ X,
                                                   const _Float16* __restrict__ WT,
                                                   const float* __restrict__ dinv,
                                                   _Float16* __restrict__ Z, int M) {
    __shared__ _Float16 ls[4][16 * 136];      // padded stride 136 halves
    const int tid  = threadIdx.x;
    const int w    = tid >> 6;
    const int lane = tid & 63;
    const int n16  = lane & 15;
    const int quad = lane >> 4;
    const int r0   = blockIdx.x * 64 + w * 16;

    int arow = r0 + n16; if (arow > M - 1) arow = M - 1;

    f32x4 acc[8];
#pragma unroll
    for (int c = 0; c < 8; ++c) acc[c] = (f32x4){0.f, 0.f, 0.f, 0.f};

#pragma unroll
    for (int kk = 0; kk < 4; ++kk) {
        int k0 = kk * 32 + quad * 8;
        f16x8 a = afrag_load(X, arow, k0);
#pragma unroll
        for (int c = 0; c < 8; ++c) {
            f16x8 b = *(const f16x8*)(WT + (size_t)(c * 16 + n16) * NF + k0);
            acc[c] = __builtin_amdgcn_mfma_f32_16x16x32_f16(a, b, acc[c], 0, 0, 0);
        }
    }

    // epilogue: scale by dinv[row], fp16, repack via LDS for coalesced stores
#pragma unroll
    for (int reg = 0; reg < 4; ++reg) {
        int lrow = quad * 4 + reg;
        int grow = r0 + lrow; if (grow > M - 1) grow = M - 1;
        float di = dinv[grow];
#pragma unroll
        for (int c = 0; c < 8; ++c)
            ls[w][lrow * 136 + c * 16 + n16] = (_Float16)(acc[c][reg] * di);
    }
    __syncthreads();
#pragma unroll
    for (int i = 0; i < 4; ++i) {
        int off16 = i * 64 + lane;            // 16B chunk index in this wave's tile
        int row = off16 >> 4;
        int col = off16 & 15;
        int grow = r0 + row;
        if (grow < M) {
            f16x8 v = *(const f16x8*)(&ls[w][row * 136 + col * 8]);
            *(f16x8*)(Z + (size_t)grow * NF + col * 8) = v;
        }
    }
}

// ---------------- aggregation, 128-wide, dual-edge 8B gathers (R7 shape) ----------------
// 1 wave per node. lane = (half, li): half = edge parity, li = 4-feature chunk.
// Each gather instr: 64 lanes x 8B = 2 edges x 256B of row data.
__global__ __launch_bounds__(256) void k_agg128h(const _Float16* __restrict__ z,
                                                 const float* __restrict__ dinv,
                                                 const int* __restrict__ offs_p,
                                                 const int* __restrict__ bsums,
                                                 const unsigned int* __restrict__ erec,
                                                 const float* __restrict__ bias,
                                                 _Float16* __restrict__ hout, int relu) {
    const int tid  = threadIdx.x;
    const int lane = tid & 63;
    const int half = lane >> 5;      // edge parity
    const int li   = lane & 31;      // feature chunk [li*4, li*4+4)
    int n = __builtin_amdgcn_readfirstlane(blockIdx.x * 4 + (tid >> 6));

    float acc0 = 0.f, acc1 = 0.f, acc2 = 0.f, acc3 = 0.f;

    int s = offs_p[n] + bsums[n >> 10];
    int e = (n + 1 < NN) ? offs_p[n + 1] + bsums[(n + 1) >> 10] : NE;
    for (int base = s; base < e; base += 64) {
        int cnt = e - base; if (cnt > 64) cnt = 64;
        unsigned int rec = 0u;
        if (lane < cnt) rec = __builtin_nontemporal_load(erec + base + lane);
        int   my_s = rec & 0xFFFF;
        float my_w = rec_w(rec);
        int k = 0;
        for (; k + 7 < cnt; k += 8) {
            int e0 = k + half, e1 = k + 2 + half, e2 = k + 4 + half, e3 = k + 6 + half;
            int s0 = __shfl(my_s, e0, 64), s1 = __shfl(my_s, e1, 64);
            int s2 = __shfl(my_s, e2, 64), s3 = __shfl(my_s, e3, 64);
            float w0 = __shfl(my_w, e0, 64), w1 = __shfl(my_w, e1, 64);
            float w2 = __shfl(my_w, e2, 64), w3 = __shfl(my_w, e3, 64);
            f16x4 v0 = *(const f16x4*)(z + ((size_t)s0 << 7) + li * 4);
            f16x4 v1 = *(const f16x4*)(z + ((size_t)s1 << 7) + li * 4);
            f16x4 v2 = *(const f16x4*)(z + ((size_t)s2 << 7) + li * 4);
            f16x4 v3 = *(const f16x4*)(z + ((size_t)s3 << 7) + li * 4);
            acc0 = fmaf((float)v0[0], w0, acc0); acc1 = fmaf((float)v0[1], w0, acc1);
            acc2 = fmaf((float)v0[2], w0, acc2); acc3 = fmaf((float)v0[3], w0, acc3);
            acc0 = fmaf((float)v1[0], w1, acc0); acc1 = fmaf((float)v1[1], w1, acc1);
            acc2 = fmaf((float)v1[2], w1, acc2); acc3 = fmaf((float)v1[3], w1, acc3);
            acc0 = fmaf((float)v2[0], w2, acc0); acc1 = fmaf((float)v2[1], w2, acc1);
            acc2 = fmaf((float)v2[2], w2, acc2); acc3 = fmaf((float)v2[3], w2, acc3);
            acc0 = fmaf((float)v3[0], w3, acc0); acc1 = fmaf((float)v3[1], w3, acc1);
            acc2 = fmaf((float)v3[2], w3, acc2); acc3 = fmaf((float)v3[3], w3, acc3);
        }
        for (; k < cnt; k += 2) {
            int eidx = k + half;
            int ec = eidx < cnt ? eidx : cnt - 1;
            int   s0 = __shfl(my_s, ec, 64);
            float wt = __shfl(my_w, ec, 64);
            float w0 = (eidx < cnt) ? wt : 0.0f;
            f16x4 v0 = *(const f16x4*)(z + ((size_t)s0 << 7) + li * 4);
            acc0 = fmaf((float)v0[0], w0, acc0); acc1 = fmaf((float)v0[1], w0, acc1);
            acc2 = fmaf((float)v0[2], w0, acc2); acc3 = fmaf((float)v0[3], w0, acc3);
        }
    }
    // merge edge-parity halves
    acc0 += __shfl_xor(acc0, 32, 64);
    acc1 += __shfl_xor(acc1, 32, 64);
    acc2 += __shfl_xor(acc2, 32, 64);
    acc3 += __shfl_xor(acc3, 32, 64);

    // self + bias + relu
    f16x4 sv = *(const f16x4*)(z + ((size_t)n << 7) + li * 4);
    float di = dinv[n];
    float4 bb = *(const float4*)(bias + li * 4);
    float r0 = fmaf(di, (float)sv[0] + acc0, bb.x);
    float r1 = fmaf(di, (float)sv[1] + acc1, bb.y);
    float r2 = fmaf(di, (float)sv[2] + acc2, bb.z);
    float r3 = fmaf(di, (float)sv[3] + acc3, bb.w);
    if (relu) {
        r0 = fmaxf(r0, 0.0f); r1 = fmaxf(r1, 0.0f);
        r2 = fmaxf(r2, 0.0f); r3 = fmaxf(r3, 0.0f);
    }
    if (half == 0) {
        f16x4 o;
        o[0] = (_Float16)r0; o[1] = (_Float16)r1;
        o[2] = (_Float16)r2; o[3] = (_Float16)r3;
        __builtin_nontemporal_store(o, (f16x4*)(hout + ((size_t)n << 7) + li * 4));
    }
}

// ---------------- GEMM: Z3[M,16](fp16) = dinv ⊙ (H[M,128](fp16) @ W3[128,16]) ----------------
__global__ __launch_bounds__(256) void k_gemm16(const _Float16* __restrict__ H,
                                                const float* __restrict__ W3,
                                                const float* __restrict__ dinv,
                                                _Float16* __restrict__ Z3, int M) {
    __shared__ float Wl[NF * NO];
    __shared__ float Hs[16 * 132];
    int tid = threadIdx.x;
    for (int i = tid; i < NF * NO; i += 256) Wl[i] = W3[i];
    int n0 = blockIdx.x * 16;
    {
        int row = tid >> 4, h8 = tid & 15;
        int gr = n0 + row; if (gr > M - 1) gr = M - 1;
        f16x8 v = *(const f16x8*)(H + (size_t)gr * NF + h8 * 8);
        float4 f0 = {(float)v[0], (float)v[1], (float)v[2], (float)v[3]};
        float4 f1 = {(float)v[4], (float)v[5], (float)v[6], (float)v[7]};
        *(float4*)(&Hs[row * 132 + h8 * 8])     = f0;
        *(float4*)(&Hs[row * 132 + h8 * 8 + 4]) = f1;
    }
    __syncthreads();
    int ln = tid >> 4, c = tid & 15;
    float acc = 0.0f;
#pragma unroll 8
    for (int k = 0; k < NF; ++k) acc = fmaf(Hs[ln * 132 + k], Wl[k * NO + c], acc);
    int n = n0 + ln;
    if (n < M) Z3[(size_t)n * NO + c] = (_Float16)(acc * dinv[n]);
}

// ---------------- final aggregation (16-wide, fp16 table) + bias + log_softmax ----------------
__global__ __launch_bounds__(256) void k_agg16_ls(const _Float16* __restrict__ z3,
                                                  const float* __restrict__ dinv,
                                                  const int* __restrict__ offs_p,
                                                  const int* __restrict__ bsums,
                                                  const unsigned int* __restrict__ erec,
                                                  const float* __restrict__ bias,
                                                  float* __restrict__ out) {
    int tid = threadIdx.x;
    int ln = tid >> 4, c = tid & 15;
    int n = blockIdx.x * 16 + ln;
    float acc = (float)z3[((size_t)n << 4) + c];
    int s = offs_p[n] + bsums[n >> 10];
    int e = (n + 1 < NN) ? offs_p[n + 1] + bsums[(n + 1) >> 10] : NE;
    int j = s;
    for (; j + 1 < e; j += 2) {
        unsigned int r0 = erec[j], r1 = erec[j + 1];
        acc = fmaf((float)z3[((size_t)(r0 & 0xFFFF) << 4) + c], rec_w(r0), acc);
        acc = fmaf((float)z3[((size_t)(r1 & 0xFFFF) << 4) + c], rec_w(r1), acc);
    }
    if (j < e) {
        unsigned int r0 = erec[j];
        acc = fmaf((float)z3[((size_t)(r0 & 0xFFFF) << 4) + c], rec_w(r0), acc);
    }
    acc = fmaf(dinv[n], acc, bias[c]);
    float m = acc;
#pragma unroll
    for (int off = 8; off > 0; off >>= 1) m = fmaxf(m, __shfl_xor(m, off, 16));
    float ex = expf(acc - m);
    float ss = ex;
#pragma unroll
    for (int off = 8; off > 0; off >>= 1) ss += __shfl_xor(ss, off, 16);
    out[(size_t)n * NO + c] = acc - m - logf(ss);
}

// ---------------- launch ----------------

extern "C" void kernel_launch(void* const* d_in, const int* in_sizes, int n_in,
                              void* d_out, int out_size, void* d_ws, size_t ws_size,
                              hipStream_t stream) {
    const float* x   = (const float*)d_in[0];
    const int*   esrc= (const int*)  d_in[1];
    const int*   edst= (const int*)  d_in[2];
    const float* ew  = (const float*)d_in[3];
    const float* W1  = (const float*)d_in[4];
    const float* b1  = (const float*)d_in[5];
    const float* W2  = (const float*)d_in[6];
    const float* b2  = (const float*)d_in[7];
    const float* W3  = (const float*)d_in[8];
    const float* b3  = (const float*)d_in[9];
    float* out = (float*)d_out;

    // workspace carve
    char* p = (char*)d_ws;
    _Float16* z   = (_Float16*)p; p += (size_t)NN * NF * 2;   // row-major, 12.8 MB
    _Float16* h   = (_Float16*)p; p += (size_t)NN * NF * 2;   // row-major, 12.8 MB
    _Float16* z3  = (_Float16*)p; p += (size_t)NN * NO * 2;   // 1.6 MB
    float* dinv   = (float*)p; p += (size_t)NN * 4;
    unsigned int* erec = (unsigned int*)p; p += (size_t)NE * 4;  // packed 4B records
    int*   rank   = (int*)p;   p += (size_t)NE * 4;
    // zeroed region: pcnt | pdeg | done  (single memset)
    int*   pcnt   = (int*)p;   p += (size_t)NPART * NN * 4;   // 3.2 MB
    float* pdeg   = (float*)p; p += (size_t)NPART * NN * 4;   // 3.2 MB
    int*   done   = (int*)p;   p += 64;
    int*   offs_p = (int*)p;   p += (size_t)(NN + 1) * 4;
    int*   bsums  = (int*)p;   p += 256;
    _Float16* W1T = (_Float16*)p; p += (size_t)NF * NF * 2;
    _Float16* W2T = (_Float16*)p; p += (size_t)NF * NF * 2;

    hipMemsetAsync(pcnt, 0, (size_t)NPART * NN * 4 * 2 + 64, stream);

    k_count_rank<<<EBL + 64, 256, 0, stream>>>(edst, ew, pcnt, pdeg, rank, NE,
                                               W1, W2, W1T, W2T);
    k_scan1f<<<NB_SCAN, SCAN_B, 0, stream>>>(pcnt, pdeg, offs_p, bsums, dinv, done);
    k_scatter<<<EBL, 256, 0, stream>>>(esrc, edst, ew, pcnt, rank, offs_p, bsums, erec, NE);

    // layer 1
    k_gemm_mfma<float><<<(NN + 63) / 64, 256, 0, stream>>>(x, W1T, dinv, z, NN);
    k_agg128h<<<NN / 4, 256, 0, stream>>>(z, dinv, offs_p, bsums, erec, b1, h, 1);
    // layer 2
    k_gemm_mfma<_Float16><<<(NN + 63) / 64, 256, 0, stream>>>(h, W2T, dinv, z, NN);
    k_agg128h<<<NN / 4, 256, 0, stream>>>(z, dinv, offs_p, bsums, erec, b2, h, 1);
    // layer 3
    k_gemm16<<<(NN + 15) / 16, 256, 0, stream>>>(h, W3, dinv, z3, NN);
    k_agg16_ls<<<NN / 16, 256, 0, stream>>>(z3, dinv, offs_p, bsums, erec, b3, out);
}

// Round 10
// 249.736 us; speedup vs baseline: 1.2409x; 1.0942x over previous
//
#include <hip/hip_runtime.h>
#include <math.h>

#define NN 50000
#define NE 500000
#define NF 128
#define NO 16
#define SCAN_B 1024
#define NB_SCAN 49   // (NN+SCAN_B-1)/SCAN_B
#define NPART 16
#define EB4 489      // blocks of 1024 edges (4/thread)
#define EB2 977      // blocks of 512 edges (2/thread)

static_assert(NN < 65536, "src must fit u16");

typedef _Float16 f16x8 __attribute__((ext_vector_type(8)));
typedef _Float16 f16x4 __attribute__((ext_vector_type(4)));
typedef float f32x4 __attribute__((ext_vector_type(4)));

union HU { unsigned short u; _Float16 h; };

__device__ inline float rec_w(unsigned int rec) {
    HU cu; cu.u = (unsigned short)(rec >> 16);
    return (float)cu.h;
}

// ---------------- graph preprocessing (atomic-light CSR build) ----------------
// Edge partition for rank disambiguation: part(e) = (e >> 10) & 15.

// pass 1: per-edge rank within (partition, dst) via returning atomics, 4 edges
// per thread for memory-level parallelism; spare blocks transpose W1/W2 to fp16.
__global__ __launch_bounds__(256) void k_count_rank(const int* __restrict__ dst,
                                                    int* __restrict__ pcnt,
                                                    int* __restrict__ rank, int E,
                                                    const float* __restrict__ W1,
                                                    const float* __restrict__ W2,
                                                    _Float16* __restrict__ W1T,
                                                    _Float16* __restrict__ W2T) {
    int b = blockIdx.x;
    if (b < EB4 - 1) {
        int part = b & (NPART - 1);
        int e0 = b * 1024 + threadIdx.x;
        int d0 = dst[e0], d1 = dst[e0 + 256], d2 = dst[e0 + 512], d3 = dst[e0 + 768];
        int r0 = atomicAdd(&pcnt[part * NN + d0], 1);
        int r1 = atomicAdd(&pcnt[part * NN + d1], 1);
        int r2 = atomicAdd(&pcnt[part * NN + d2], 1);
        int r3 = atomicAdd(&pcnt[part * NN + d3], 1);
        rank[e0]       = r0;
        rank[e0 + 256] = r1;
        rank[e0 + 512] = r2;
        rank[e0 + 768] = r3;
    } else if (b == EB4 - 1) {
        int part = b & (NPART - 1);
#pragma unroll
        for (int k = 0; k < 4; ++k) {
            int e = b * 1024 + k * 256 + threadIdx.x;
            if (e < E) {
                int d = dst[e];
                rank[e] = atomicAdd(&pcnt[part * NN + d], 1);
            }
        }
    } else {
        int idx = (b - EB4) * 256 + threadIdx.x;   // [0,16384)
        int r = idx >> 7, c = idx & 127;
        W1T[(size_t)c * NF + r] = (_Float16)W1[idx];
        W2T[(size_t)c * NF + r] = (_Float16)W2[idx];
    }
}

// pass 2: per-node partition bases (in place) + block scan of totals + fused
// 49-block top-level scan via last-block pattern (agent-scope atomics).
__global__ void k_scan1f(int* __restrict__ pcnt, int* __restrict__ offs_p,
                         int* __restrict__ bsums, int* __restrict__ done) {
    __shared__ int sm[SCAN_B];
    __shared__ int isLast;
    int t = threadIdx.x;
    int i = blockIdx.x * SCAN_B + t;
    int c = 0;
    if (i < NN) {
        int run = 0;
#pragma unroll
        for (int p = 0; p < NPART; ++p) {
            int v = pcnt[p * NN + i];
            pcnt[p * NN + i] = run;
            run += v;
        }
        c = run;
    }
    sm[t] = c;
    __syncthreads();
    for (int off = 1; off < SCAN_B; off <<= 1) {
        int x = (t >= off) ? sm[t - off] : 0;
        __syncthreads();
        sm[t] += x;
        __syncthreads();
    }
    if (i < NN) offs_p[i] = sm[t] - c;
    if (t == SCAN_B - 1) {
        __hip_atomic_store(&bsums[blockIdx.x], sm[t], __ATOMIC_RELEASE,
                           __HIP_MEMORY_SCOPE_AGENT);
        int old = __hip_atomic_fetch_add(done, 1, __ATOMIC_ACQ_REL,
                                         __HIP_MEMORY_SCOPE_AGENT);
        isLast = (old == (int)gridDim.x - 1) ? 1 : 0;
    }
    __syncthreads();
    if (isLast && t < 64) {
        int v = (t < NB_SCAN) ? __hip_atomic_load(&bsums[t], __ATOMIC_ACQUIRE,
                                                  __HIP_MEMORY_SCOPE_AGENT) : 0;
        int orig = v;
#pragma unroll
        for (int off = 1; off < 64; off <<= 1) {
            int u = __shfl_up(v, off, 64);
            if (t >= off) v += u;
        }
        if (t < NB_SCAN)
            __hip_atomic_store(&bsums[t], v - orig, __ATOMIC_RELEASE,
                               __HIP_MEMORY_SCOPE_AGENT);
    }
}

// pass 3: atomic-free scatter of packed 4B {src:u16, ew:fp16} records, 2/thread
__global__ __launch_bounds__(256) void k_scatter(const int* __restrict__ src,
                                                 const int* __restrict__ dst,
                                                 const float* __restrict__ ew,
                                                 const int* __restrict__ pcnt,
                                                 const int* __restrict__ rank,
                                                 const int* __restrict__ offs_p,
                                                 const int* __restrict__ bsums,
                                                 unsigned int* __restrict__ erec, int E) {
    int b = blockIdx.x;
#pragma unroll
    for (int k = 0; k < 2; ++k) {
        int e = b * 512 + k * 256 + threadIdx.x;
        if (e < E) {
            int part = (e >> 10) & (NPART - 1);
            int d = dst[e];
            int pos = offs_p[d] + bsums[d >> 10] + pcnt[part * NN + d] + rank[e];
            HU cu; cu.h = (_Float16)ew[e];
            erec[pos] = (unsigned int)src[e] | ((unsigned int)cu.u << 16);
        }
    }
}

// pass 4: deg from CSR -> dinv
__global__ void k_dinv_csr(const unsigned int* __restrict__ erec,
                           const int* __restrict__ offs_p, const int* __restrict__ bsums,
                           float* __restrict__ dinv) {
    int n = blockIdx.x * blockDim.x + threadIdx.x;
    if (n < NN) {
        int s = offs_p[n] + bsums[n >> 10];
        int e = (n + 1 < NN) ? offs_p[n + 1] + bsums[(n + 1) >> 10] : NE;
        float deg = 1.0f;
        for (int j = s; j < e; ++j) deg += rec_w(erec[j]);
        dinv[n] = rsqrtf(deg);
    }
}

// ---------------- MFMA GEMM: Z[M,128](fp16, row-major) = dinv ⊙ (X @ W) ----------------

__device__ inline f16x8 afrag_load(const float* X, int row, int k0) {
    const float4* p = (const float4*)(X + (size_t)row * NF + k0);
    float4 a = p[0], b = p[1];
    f16x8 r;
    r[0] = (_Float16)a.x; r[1] = (_Float16)a.y; r[2] = (_Float16)a.z; r[3] = (_Float16)a.w;
    r[4] = (_Float16)b.x; r[5] = (_Float16)b.y; r[6] = (_Float16)b.z; r[7] = (_Float16)b.w;
    return r;
}
__device__ inline f16x8 afrag_load(const _Float16* X, int row, int k0) {
    return *(const f16x8*)(X + (size_t)row * NF + k0);
}

template <typename TA>
__global__ __launch_bounds__(256) void k_gemm_mfma(const TA* __restrict__ X,
                                                   const _Float16* __restrict__ WT,
                                                   const float* __restrict__ dinv,
                                                   _Float16* __restrict__ Z, int M) {
    __shared__ _Float16 ls[4][16 * 136];      // padded stride 136 halves
    const int tid  = threadIdx.x;
    const int w    = tid >> 6;
    const int lane = tid & 63;
    const int n16  = lane & 15;
    const int quad = lane >> 4;
    const int r0   = blockIdx.x * 64 + w * 16;

    int arow = r0 + n16; if (arow > M - 1) arow = M - 1;

    f32x4 acc[8];
#pragma unroll
    for (int c = 0; c < 8; ++c) acc[c] = (f32x4){0.f, 0.f, 0.f, 0.f};

#pragma unroll
    for (int kk = 0; kk < 4; ++kk) {
        int k0 = kk * 32 + quad * 8;
        f16x8 a = afrag_load(X, arow, k0);
#pragma unroll
        for (int c = 0; c < 8; ++c) {
            f16x8 b = *(const f16x8*)(WT + (size_t)(c * 16 + n16) * NF + k0);
            acc[c] = __builtin_amdgcn_mfma_f32_16x16x32_f16(a, b, acc[c], 0, 0, 0);
        }
    }

#pragma unroll
    for (int reg = 0; reg < 4; ++reg) {
        int lrow = quad * 4 + reg;
        int grow = r0 + lrow; if (grow > M - 1) grow = M - 1;
        float di = dinv[grow];
#pragma unroll
        for (int c = 0; c < 8; ++c)
            ls[w][lrow * 136 + c * 16 + n16] = (_Float16)(acc[c][reg] * di);
    }
    __syncthreads();
#pragma unroll
    for (int i = 0; i < 4; ++i) {
        int off16 = i * 64 + lane;
        int row = off16 >> 4;
        int col = off16 & 15;
        int grow = r0 + row;
        if (grow < M) {
            f16x8 v = *(const f16x8*)(&ls[w][row * 136 + col * 8]);
            *(f16x8*)(Z + (size_t)grow * NF + col * 8) = v;
        }
    }
}

// ---------------- aggregation, 128-wide, dual-edge 8B gathers ----------------
__global__ __launch_bounds__(256) void k_agg128h(const _Float16* __restrict__ z,
                                                 const float* __restrict__ dinv,
                                                 const int* __restrict__ offs_p,
                                                 const int* __restrict__ bsums,
                                                 const unsigned int* __restrict__ erec,
                                                 const float* __restrict__ bias,
                                                 _Float16* __restrict__ hout, int relu) {
    const int tid  = threadIdx.x;
    const int lane = tid & 63;
    const int half = lane >> 5;      // edge parity
    const int li   = lane & 31;      // feature chunk [li*4, li*4+4)
    int n = __builtin_amdgcn_readfirstlane(blockIdx.x * 4 + (tid >> 6));

    float acc0 = 0.f, acc1 = 0.f, acc2 = 0.f, acc3 = 0.f;

    int s = offs_p[n] + bsums[n >> 10];
    int e = (n + 1 < NN) ? offs_p[n + 1] + bsums[(n + 1) >> 10] : NE;
    for (int base = s; base < e; base += 64) {
        int cnt = e - base; if (cnt > 64) cnt = 64;
        unsigned int rec = 0u;
        if (lane < cnt) rec = __builtin_nontemporal_load(erec + base + lane);
        int   my_s = rec & 0xFFFF;
        float my_w = rec_w(rec);
        int k = 0;
        for (; k + 7 < cnt; k += 8) {
            int e0 = k + half, e1 = k + 2 + half, e2 = k + 4 + half, e3 = k + 6 + half;
            int s0 = __shfl(my_s, e0, 64), s1 = __shfl(my_s, e1, 64);
            int s2 = __shfl(my_s, e2, 64), s3 = __shfl(my_s, e3, 64);
            float w0 = __shfl(my_w, e0, 64), w1 = __shfl(my_w, e1, 64);
            float w2 = __shfl(my_w, e2, 64), w3 = __shfl(my_w, e3, 64);
            f16x4 v0 = *(const f16x4*)(z + ((size_t)s0 << 7) + li * 4);
            f16x4 v1 = *(const f16x4*)(z + ((size_t)s1 << 7) + li * 4);
            f16x4 v2 = *(const f16x4*)(z + ((size_t)s2 << 7) + li * 4);
            f16x4 v3 = *(const f16x4*)(z + ((size_t)s3 << 7) + li * 4);
            acc0 = fmaf((float)v0[0], w0, acc0); acc1 = fmaf((float)v0[1], w0, acc1);
            acc2 = fmaf((float)v0[2], w0, acc2); acc3 = fmaf((float)v0[3], w0, acc3);
            acc0 = fmaf((float)v1[0], w1, acc0); acc1 = fmaf((float)v1[1], w1, acc1);
            acc2 = fmaf((float)v1[2], w1, acc2); acc3 = fmaf((float)v1[3], w1, acc3);
            acc0 = fmaf((float)v2[0], w2, acc0); acc1 = fmaf((float)v2[1], w2, acc1);
            acc2 = fmaf((float)v2[2], w2, acc2); acc3 = fmaf((float)v2[3], w2, acc3);
            acc0 = fmaf((float)v3[0], w3, acc0); acc1 = fmaf((float)v3[1], w3, acc1);
            acc2 = fmaf((float)v3[2], w3, acc2); acc3 = fmaf((float)v3[3], w3, acc3);
        }
        for (; k < cnt; k += 2) {
            int eidx = k + half;
            int ec = eidx < cnt ? eidx : cnt - 1;
            int   s0 = __shfl(my_s, ec, 64);
            float wt = __shfl(my_w, ec, 64);
            float w0 = (eidx < cnt) ? wt : 0.0f;
            f16x4 v0 = *(const f16x4*)(z + ((size_t)s0 << 7) + li * 4);
            acc0 = fmaf((float)v0[0], w0, acc0); acc1 = fmaf((float)v0[1], w0, acc1);
            acc2 = fmaf((float)v0[2], w0, acc2); acc3 = fmaf((float)v0[3], w0, acc3);
        }
    }
    acc0 += __shfl_xor(acc0, 32, 64);
    acc1 += __shfl_xor(acc1, 32, 64);
    acc2 += __shfl_xor(acc2, 32, 64);
    acc3 += __shfl_xor(acc3, 32, 64);

    f16x4 sv = *(const f16x4*)(z + ((size_t)n << 7) + li * 4);
    float di = dinv[n];
    float4 bb = *(const float4*)(bias + li * 4);
    float r0 = fmaf(di, (float)sv[0] + acc0, bb.x);
    float r1 = fmaf(di, (float)sv[1] + acc1, bb.y);
    float r2 = fmaf(di, (float)sv[2] + acc2, bb.z);
    float r3 = fmaf(di, (float)sv[3] + acc3, bb.w);
    if (relu) {
        r0 = fmaxf(r0, 0.0f); r1 = fmaxf(r1, 0.0f);
        r2 = fmaxf(r2, 0.0f); r3 = fmaxf(r3, 0.0f);
    }
    if (half == 0) {
        f16x4 o;
        o[0] = (_Float16)r0; o[1] = (_Float16)r1;
        o[2] = (_Float16)r2; o[3] = (_Float16)r3;
        __builtin_nontemporal_store(o, (f16x4*)(hout + ((size_t)n << 7) + li * 4));
    }
}

// ---------------- GEMM: Z3[M,16](fp16) = dinv ⊙ (H[M,128](fp16) @ W3[128,16]) ----------------
__global__ __launch_bounds__(256) void k_gemm16(const _Float16* __restrict__ H,
                                                const float* __restrict__ W3,
                                                const float* __restrict__ dinv,
                                                _Float16* __restrict__ Z3, int M) {
    __shared__ float Wl[NF * NO];
    __shared__ float Hs[16 * 132];
    int tid = threadIdx.x;
    for (int i = tid; i < NF * NO; i += 256) Wl[i] = W3[i];
    int n0 = blockIdx.x * 16;
    {
        int row = tid >> 4, h8 = tid & 15;
        int gr = n0 + row; if (gr > M - 1) gr = M - 1;
        f16x8 v = *(const f16x8*)(H + (size_t)gr * NF + h8 * 8);
        float4 f0 = {(float)v[0], (float)v[1], (float)v[2], (float)v[3]};
        float4 f1 = {(float)v[4], (float)v[5], (float)v[6], (float)v[7]};
        *(float4*)(&Hs[row * 132 + h8 * 8])     = f0;
        *(float4*)(&Hs[row * 132 + h8 * 8 + 4]) = f1;
    }
    __syncthreads();
    int ln = tid >> 4, c = tid & 15;
    float acc = 0.0f;
#pragma unroll 8
    for (int k = 0; k < NF; ++k) acc = fmaf(Hs[ln * 132 + k], Wl[k * NO + c], acc);
    int n = n0 + ln;
    if (n < M) Z3[(size_t)n * NO + c] = (_Float16)(acc * dinv[n]);
}

// ---------------- final aggregation (16-wide, fp16 table) + bias + log_softmax ----------------
__global__ __launch_bounds__(256) void k_agg16_ls(const _Float16* __restrict__ z3,
                                                  const float* __restrict__ dinv,
                                                  const int* __restrict__ offs_p,
                                                  const int* __restrict__ bsums,
                                                  const unsigned int* __restrict__ erec,
                                                  const float* __restrict__ bias,
                                                  float* __restrict__ out) {
    int tid = threadIdx.x;
    int ln = tid >> 4, c = tid & 15;
    int n = blockIdx.x * 16 + ln;
    float acc = (float)z3[((size_t)n << 4) + c];
    int s = offs_p[n] + bsums[n >> 10];
    int e = (n + 1 < NN) ? offs_p[n + 1] + bsums[(n + 1) >> 10] : NE;
    int j = s;
    for (; j + 1 < e; j += 2) {
        unsigned int r0 = erec[j], r1 = erec[j + 1];
        acc = fmaf((float)z3[((size_t)(r0 & 0xFFFF) << 4) + c], rec_w(r0), acc);
        acc = fmaf((float)z3[((size_t)(r1 & 0xFFFF) << 4) + c], rec_w(r1), acc);
    }
    if (j < e) {
        unsigned int r0 = erec[j];
        acc = fmaf((float)z3[((size_t)(r0 & 0xFFFF) << 4) + c], rec_w(r0), acc);
    }
    acc = fmaf(dinv[n], acc, bias[c]);
    float m = acc;
#pragma unroll
    for (int off = 8; off > 0; off >>= 1) m = fmaxf(m, __shfl_xor(m, off, 16));
    float ex = expf(acc - m);
    float ss = ex;
#pragma unroll
    for (int off = 8; off > 0; off >>= 1) ss += __shfl_xor(ss, off, 16);
    out[(size_t)n * NO + c] = acc - m - logf(ss);
}

// ---------------- launch ----------------

extern "C" void kernel_launch(void* const* d_in, const int* in_sizes, int n_in,
                              void* d_out, int out_size, void* d_ws, size_t ws_size,
                              hipStream_t stream) {
    const float* x   = (const float*)d_in[0];
    const int*   esrc= (const int*)  d_in[1];
    const int*   edst= (const int*)  d_in[2];
    const float* ew  = (const float*)d_in[3];
    const float* W1  = (const float*)d_in[4];
    const float* b1  = (const float*)d_in[5];
    const float* W2  = (const float*)d_in[6];
    const float* b2  = (const float*)d_in[7];
    const float* W3  = (const float*)d_in[8];
    const float* b3  = (const float*)d_in[9];
    float* out = (float*)d_out;

    // workspace carve
    char* p = (char*)d_ws;
    _Float16* z   = (_Float16*)p; p += (size_t)NN * NF * 2;   // 12.8 MB
    _Float16* h   = (_Float16*)p; p += (size_t)NN * NF * 2;   // 12.8 MB
    _Float16* z3  = (_Float16*)p; p += (size_t)NN * NO * 2;   // 1.6 MB
    float* dinv   = (float*)p; p += (size_t)NN * 4;
    unsigned int* erec = (unsigned int*)p; p += (size_t)NE * 4;
    int*   rank   = (int*)p;   p += (size_t)NE * 4;
    // zeroed region: pcnt | done (single memset)
    int*   pcnt   = (int*)p;   p += (size_t)NPART * NN * 4;   // 3.2 MB
    int*   done   = (int*)p;   p += 64;
    int*   offs_p = (int*)p;   p += (size_t)(NN + 1) * 4;
    int*   bsums  = (int*)p;   p += 256;
    _Float16* W1T = (_Float16*)p; p += (size_t)NF * NF * 2;
    _Float16* W2T = (_Float16*)p; p += (size_t)NF * NF * 2;

    hipMemsetAsync(pcnt, 0, (size_t)NPART * NN * 4 + 64, stream);

    k_count_rank<<<EB4 + 64, 256, 0, stream>>>(edst, pcnt, rank, NE, W1, W2, W1T, W2T);
    k_scan1f<<<NB_SCAN, SCAN_B, 0, stream>>>(pcnt, offs_p, bsums, done);
    k_scatter<<<EB2, 256, 0, stream>>>(esrc, edst, ew, pcnt, rank, offs_p, bsums, erec, NE);
    k_dinv_csr<<<(NN + 255) / 256, 256, 0, stream>>>(erec, offs_p, bsums, dinv);

    // layer 1
    k_gemm_mfma<float><<<(NN + 63) / 64, 256, 0, stream>>>(x, W1T, dinv, z, NN);
    k_agg128h<<<NN / 4, 256, 0, stream>>>(z, dinv, offs_p, bsums, erec, b1, h, 1);
    // layer 2
    k_gemm_mfma<_Float16><<<(NN + 63) / 64, 256, 0, stream>>>(h, W2T, dinv, z, NN);
    k_agg128h<<<NN / 4, 256, 0, stream>>>(z, dinv, offs_p, bsums, erec, b2, h, 1);
    // layer 3
    k_gemm16<<<(NN + 15) / 16, 256, 0, stream>>>(h, W3, dinv, z3, NN);
    k_agg16_ls<<<NN / 16, 256, 0, stream>>>(z3, dinv, offs_p, bsums, erec, b3, out);
}